// Round 1
// baseline (54.714 us; speedup 1.0000x reference)
//
#include <hip/hip_runtime.h>

#define FG_THRESH 0.7f
#define BG_HI 0.5f
#define BG_LO 0.1f
#define BATCH 256
#define FG_ROIS 128

// ---------------------------------------------------------------------------
// K1: per-roi IoU max/argmax over K gt boxes (gt boxes staged in LDS),
//     classify fg/bg, per-block candidate counts.
// ---------------------------------------------------------------------------
__global__ __launch_bounds__(256) void k_iou(
    const float* __restrict__ proposals,   // (N,4)
    const float* __restrict__ gt_boxes,    // (K,4)
    int N, int K, int M,
    int* __restrict__ gt_assign,           // [M]
    int* __restrict__ flags,               // [M] 0=none 1=fg 2=bg
    int* __restrict__ blk_counts)          // [GB][3] fg,bg,nonbg
{
    __shared__ float4 gsh[256];
    __shared__ float garea[256];
    __shared__ int wcnt[3][4];

    int tid = threadIdx.x;
    if (tid < K) {
        float4 g = ((const float4*)gt_boxes)[tid];
        gsh[tid] = g;
        garea[tid] = (g.z - g.x + 1.0f) * (g.w - g.y + 1.0f);
    }
    __syncthreads();

    int i = blockIdx.x * 256 + tid;
    int valid = (i < M);
    int fg = 0, bg = 0;
    if (valid) {
        float4 a = (i < N) ? ((const float4*)proposals)[i]
                           : ((const float4*)gt_boxes)[i - N];
        float area_a = (a.z - a.x + 1.0f) * (a.w - a.y + 1.0f);
        float best = -1.0f;
        int bestk = 0;
        for (int k = 0; k < K; ++k) {
            float4 g = gsh[k];
            float x1 = fmaxf(a.x, g.x);
            float y1 = fmaxf(a.y, g.y);
            float x2 = fminf(a.z, g.z);
            float y2 = fminf(a.w, g.w);
            float iw = fmaxf(x2 - x1 + 1.0f, 0.0f);
            float ih = fmaxf(y2 - y1 + 1.0f, 0.0f);
            float inter = iw * ih;
            float ov = inter / (area_a + garea[k] - inter);  // IEEE div, matches np
            if (ov > best) { best = ov; bestk = k; }         // first-of-max
        }
        gt_assign[i] = bestk;
        fg = (best >= FG_THRESH) ? 1 : 0;
        bg = ((best < BG_HI) && (best >= BG_LO)) ? 1 : 0;
        flags[i] = fg ? 1 : (bg ? 2 : 0);
    }
    int nb = valid && !bg;

    unsigned long long mf = __ballot(fg);
    unsigned long long mb = __ballot(bg);
    unsigned long long mn = __ballot(nb);
    int lane = tid & 63, w = tid >> 6;
    if (lane == 0) {
        wcnt[0][w] = __popcll(mf);
        wcnt[1][w] = __popcll(mb);
        wcnt[2][w] = __popcll(mn);
    }
    __syncthreads();
    if (tid == 0) {
        blk_counts[blockIdx.x * 3 + 0] = wcnt[0][0] + wcnt[0][1] + wcnt[0][2] + wcnt[0][3];
        blk_counts[blockIdx.x * 3 + 1] = wcnt[1][0] + wcnt[1][1] + wcnt[1][2] + wcnt[1][3];
        blk_counts[blockIdx.x * 3 + 2] = wcnt[2][0] + wcnt[2][1] + wcnt[2][2] + wcnt[2][3];
    }
}

// ---------------------------------------------------------------------------
// K2: single-block exclusive scan of per-block counts (GB <= 1024).
// ---------------------------------------------------------------------------
__global__ __launch_bounds__(1024) void k_scan(
    const int* __restrict__ blk_counts, int GB,
    int* __restrict__ blk_bases, int* __restrict__ totals)
{
    __shared__ int s0[1024], s1[1024], s2[1024];
    int t = threadIdx.x;
    int c0 = (t < GB) ? blk_counts[t * 3 + 0] : 0;
    int c1 = (t < GB) ? blk_counts[t * 3 + 1] : 0;
    int c2 = (t < GB) ? blk_counts[t * 3 + 2] : 0;
    s0[t] = c0; s1[t] = c1; s2[t] = c2;
    __syncthreads();
    for (int off = 1; off < 1024; off <<= 1) {
        int a0 = (t >= off) ? s0[t - off] : 0;
        int a1 = (t >= off) ? s1[t - off] : 0;
        int a2 = (t >= off) ? s2[t - off] : 0;
        __syncthreads();
        s0[t] += a0; s1[t] += a1; s2[t] += a2;
        __syncthreads();
    }
    if (t < GB) {
        blk_bases[t * 3 + 0] = s0[t] - c0;
        blk_bases[t * 3 + 1] = s1[t] - c1;
        blk_bases[t * 3 + 2] = s2[t] - c2;
    }
    if (t == 0) {
        totals[0] = s0[1023];
        totals[1] = s1[1023];
        totals[2] = s2[1023];
    }
}

// ---------------------------------------------------------------------------
// K3: emit ordered candidate lists (first FG_ROIS fg, first BATCH bg/nonbg,
//     ascending roi index == argsort-of-unique-keys semantics).
// ---------------------------------------------------------------------------
__global__ __launch_bounds__(256) void k_emit(
    const int* __restrict__ flags, int M,
    const int* __restrict__ blk_bases,
    int* __restrict__ fg_list, int* __restrict__ bg_list, int* __restrict__ nb_list)
{
    __shared__ int wcnt[3][4];
    int tid = threadIdx.x;
    int i = blockIdx.x * 256 + tid;
    int valid = (i < M);
    int f = valid ? flags[i] : 0;
    int fg = (f == 1), bg = (f == 2);
    int nb = valid && !bg;

    unsigned long long mf = __ballot(fg);
    unsigned long long mb = __ballot(bg);
    unsigned long long mn = __ballot(nb);
    int lane = tid & 63, w = tid >> 6;
    if (lane == 0) {
        wcnt[0][w] = __popcll(mf);
        wcnt[1][w] = __popcll(mb);
        wcnt[2][w] = __popcll(mn);
    }
    __syncthreads();
    int basef = 0, baseb = 0, basen = 0;
    for (int x = 0; x < w; ++x) {
        basef += wcnt[0][x]; baseb += wcnt[1][x]; basen += wcnt[2][x];
    }
    unsigned long long lmask = (1ull << lane) - 1ull;
    if (fg) {
        int r = blk_bases[blockIdx.x * 3 + 0] + basef + __popcll(mf & lmask);
        if (r < FG_ROIS) fg_list[r] = i;
    }
    if (bg) {
        int r = blk_bases[blockIdx.x * 3 + 1] + baseb + __popcll(mb & lmask);
        if (r < BATCH) bg_list[r] = i;
    }
    if (nb) {
        int r = blk_bases[blockIdx.x * 3 + 2] + basen + __popcll(mn & lmask);
        if (r < BATCH) nb_list[r] = i;
    }
}

// ---------------------------------------------------------------------------
// K4: build keep[], class, bbox-transform targets; write rois output.
// ---------------------------------------------------------------------------
__global__ __launch_bounds__(256) void k_meta(
    const float* __restrict__ proposals,
    const float* __restrict__ gt_boxes,
    const float* __restrict__ gt_labels,   // (K, C)
    int N, int C,
    const int* __restrict__ gt_assign,
    const int* __restrict__ totals,
    const int* __restrict__ fg_list,
    const int* __restrict__ bg_list,
    const int* __restrict__ nb_list,
    int* __restrict__ meta_i,              // [BATCH][4]: keep,is_fg,cls,ga
    float* __restrict__ meta_f,            // [BATCH][4]: tx,ty,tw,th
    float* __restrict__ out_rois)          // (BATCH,4)
{
    int pos = threadIdx.x;
    int num_fg = totals[0], num_bg = totals[1];
    int fg_take = min(FG_ROIS, num_fg);
    int is_fg = (pos < fg_take) ? 1 : 0;
    int keep;
    if (is_fg) {
        keep = fg_list[pos];
    } else {
        int j = pos - fg_take;
        keep = (j < num_bg) ? bg_list[j] : nb_list[j - num_bg];
    }
    float4 a = (keep < N) ? ((const float4*)proposals)[keep]
                          : ((const float4*)gt_boxes)[keep - N];
    int ga = gt_assign[keep];
    float4 g = ((const float4*)gt_boxes)[ga];

    float ew = a.z - a.x + 1.0f, eh = a.w - a.y + 1.0f;
    float ecx = a.x + 0.5f * ew, ecy = a.y + 0.5f * eh;
    float gw = g.z - g.x + 1.0f, gh = g.w - g.y + 1.0f;
    float gcx = g.x + 0.5f * gw, gcy = g.y + 0.5f * gh;
    float tx = (gcx - ecx) / ew;
    float ty = (gcy - ecy) / eh;
    float tw = logf(gw / ew);
    float th = logf(gh / eh);

    int cls = 0;
    if (is_fg) {
        const float* lr = gt_labels + (size_t)ga * C;
        float b = lr[0]; int bi = 0;
        for (int c = 1; c < C; ++c) {
            float v = lr[c];
            if (v > b) { b = v; bi = c; }
        }
        cls = bi;
    }

    meta_i[pos * 4 + 0] = keep;
    meta_i[pos * 4 + 1] = is_fg;
    meta_i[pos * 4 + 2] = cls;
    meta_i[pos * 4 + 3] = ga;
    meta_f[pos * 4 + 0] = tx;
    meta_f[pos * 4 + 1] = ty;
    meta_f[pos * 4 + 2] = tw;
    meta_f[pos * 4 + 3] = th;

    out_rois[pos * 4 + 0] = a.x;
    out_rois[pos * 4 + 1] = a.y;
    out_rois[pos * 4 + 2] = a.z;
    out_rois[pos * 4 + 3] = a.w;
}

// ---------------------------------------------------------------------------
// K5: elementwise labels (BATCH x C) and bbox_targets (BATCH x 4C) writes.
// ---------------------------------------------------------------------------
__global__ __launch_bounds__(256) void k_out(
    const float* __restrict__ gt_labels, int C,
    const int* __restrict__ meta_i,
    const float* __restrict__ meta_f,
    float* __restrict__ out_labels,
    float* __restrict__ out_bbox)
{
    int t = blockIdx.x * 256 + threadIdx.x;
    int LBL = BATCH * C;
    int BBX = BATCH * 4 * C;
    if (t < LBL) {
        int pos = t / C, c = t - pos * C;
        float v;
        if (meta_i[pos * 4 + 1]) {
            v = gt_labels[(size_t)meta_i[pos * 4 + 3] * C + c];
        } else {
            v = (c == 0) ? 1.0f : 0.0f;
        }
        out_labels[t] = v;
    } else if (t < LBL + BBX) {
        int u = t - LBL;
        int pos = u / (4 * C), idx = u - pos * (4 * C);
        int c = idx >> 2, d = idx & 3;
        int cls = meta_i[pos * 4 + 2];
        out_bbox[u] = (cls > 0 && c == cls) ? meta_f[pos * 4 + d] : 0.0f;
    }
}

// ---------------------------------------------------------------------------
extern "C" void kernel_launch(void* const* d_in, const int* in_sizes, int n_in,
                              void* d_out, int out_size, void* d_ws, size_t ws_size,
                              hipStream_t stream)
{
    const float* proposals = (const float*)d_in[0];
    const float* gt_labels = (const float*)d_in[1];
    const float* gt_boxes  = (const float*)d_in[2];
    int N = in_sizes[0] / 4;           // 80000
    int K = in_sizes[2] / 4;           // 256
    int C = in_sizes[1] / K;           // 81
    int M = N + K;                     // 80256
    int GB = (M + 255) / 256;          // 314

    char* ws = (char*)d_ws;
    size_t off = 0;
    auto alloc = [&](size_t bytes) -> void* {
        void* p = ws + off;
        off += (bytes + 255) & ~(size_t)255;
        return p;
    };
    int*   gt_assign  = (int*)  alloc((size_t)M * 4);
    int*   flags      = (int*)  alloc((size_t)M * 4);
    int*   blk_counts = (int*)  alloc((size_t)GB * 3 * 4);
    int*   blk_bases  = (int*)  alloc((size_t)GB * 3 * 4);
    int*   totals     = (int*)  alloc(4 * 4);
    int*   fg_list    = (int*)  alloc(FG_ROIS * 4);
    int*   bg_list    = (int*)  alloc(BATCH * 4);
    int*   nb_list    = (int*)  alloc(BATCH * 4);
    int*   meta_i     = (int*)  alloc(BATCH * 4 * 4);
    float* meta_f     = (float*)alloc(BATCH * 4 * 4);

    float* out_rois   = (float*)d_out;               // (1,BATCH,4)
    float* out_labels = out_rois + BATCH * 4;        // (1,BATCH,C)
    float* out_bbox   = out_labels + BATCH * C;      // (1,BATCH,4C)

    k_iou<<<GB, 256, 0, stream>>>(proposals, gt_boxes, N, K, M,
                                  gt_assign, flags, blk_counts);
    k_scan<<<1, 1024, 0, stream>>>(blk_counts, GB, blk_bases, totals);
    k_emit<<<GB, 256, 0, stream>>>(flags, M, blk_bases, fg_list, bg_list, nb_list);
    k_meta<<<1, BATCH, 0, stream>>>(proposals, gt_boxes, gt_labels, N, C,
                                    gt_assign, totals, fg_list, bg_list, nb_list,
                                    meta_i, meta_f, out_rois);
    int tot = BATCH * C + BATCH * 4 * C;
    k_out<<<(tot + 255) / 256, 256, 0, stream>>>(gt_labels, C, meta_i, meta_f,
                                                 out_labels, out_bbox);
}